// Round 4
// baseline (373.516 us; speedup 1.0000x reference)
//
#include <hip/hip_runtime.h>
#include <math.h>

#define NDIM 512
#define NROWS 256  // B*S = 2*128

typedef float vfloat4 __attribute__((ext_vector_type(4)));

// ---------------------------------------------------------------------------
// Zero-fill of the std_mat region (256 MB) with PLAIN cached dwordx4 stores.
// R3's nontemporal variant ran at ~1.5 TB/s useful with 4x HBM write
// amplification (NT bypasses L2 -> 16B granule vs 64B memory atom theory).
// Cached stores write-allocate in L2 and evict full lines -> expect 1x
// WRITE_SIZE (262144 KB) at ~6 TB/s (~45 us).
// 2048 blocks x 256 threads x 32 iters x 16B = 256 MiB; each block fills a
// contiguous 512 KiB chunk, waves fully coalesced.
// ---------------------------------------------------------------------------
__global__ __launch_bounds__(256) void gs_fill(float* __restrict__ std_base) {
    vfloat4* p = (vfloat4*)std_base;
    size_t idx = (size_t)blockIdx.x * (256 * 32) + threadIdx.x;
    const vfloat4 z = {0.f, 0.f, 0.f, 0.f};
    #pragma unroll 8
    for (int it = 0; it < 32; ++it) {
        p[idx] = z;
        idx += 256;
    }
}

// ---------------------------------------------------------------------------
// GEMM + softplus + sample + diagonal scatter. R1-proven shape (~14 us):
// 256 blocks x 256 threads, one block per row; x row staged in LDS
// (wave-uniform broadcast reads); thread handles cols {tid, tid+256}, each
// with both the softplus half (row c of W) and mu half (row c+512).
// Per-CU W traffic: 2 MB through L1 (~13 us floor). Runs AFTER gs_fill.
// ---------------------------------------------------------------------------
__global__ __launch_bounds__(256) void gs_gemm(const float* __restrict__ x,
                                               const float* __restrict__ W,
                                               const float* __restrict__ b,
                                               const float* __restrict__ eps,
                                               float* __restrict__ out) {
    __shared__ float xs[NDIM];
    const int r = blockIdx.x;
    const int tid = threadIdx.x;

    const float* xrow = x + (size_t)r * NDIM;
    xs[tid] = xrow[tid];
    xs[tid + 256] = xrow[tid + 256];
    __syncthreads();

    float* out_sample = out;
    float* out_mu     = out + (size_t)NROWS * NDIM;
    float* out_std    = out + (size_t)2 * NROWS * NDIM;

    const float4* xs4 = (const float4*)xs;

    for (int ii = tid; ii < NDIM; ii += 256) {
        const float4* wa = (const float4*)(W + (size_t)ii * NDIM);          // softplus half
        const float4* wb = (const float4*)(W + (size_t)(ii + NDIM) * NDIM); // mu half
        float s0 = 0.f, s1 = 0.f;
        #pragma unroll 8
        for (int k = 0; k < NDIM / 4; ++k) {
            float4 xv = xs4[k];   // wave-uniform -> LDS broadcast, conflict-free
            float4 a  = wa[k];
            float4 c  = wb[k];
            s0 += xv.x * a.x + xv.y * a.y + xv.z * a.z + xv.w * a.w;
            s1 += xv.x * c.x + xv.y * c.y + xv.z * c.z + xv.w * c.w;
        }
        s0 += b[ii];
        s1 += b[ii + NDIM];

        const float var = (s0 > 20.f) ? s0 : log1pf(expf(s0));  // softplus, stable
        const float mu  = s1;
        const float smp = mu + sqrtf(var) * eps[(size_t)r * NDIM + ii];

        out_sample[(size_t)r * NDIM + ii] = smp;
        out_mu[(size_t)r * NDIM + ii]     = mu;
        out_std[(size_t)r * NDIM * NDIM + (size_t)ii * NDIM + ii] = var;
    }
}

extern "C" void kernel_launch(void* const* d_in, const int* in_sizes, int n_in,
                              void* d_out, int out_size, void* d_ws, size_t ws_size,
                              hipStream_t stream) {
    const float* x   = (const float*)d_in[0];
    const float* W   = (const float*)d_in[1];
    const float* b   = (const float*)d_in[2];
    const float* eps = (const float*)d_in[3];
    float* out = (float*)d_out;

    float* std_base = out + (size_t)2 * NROWS * NDIM;  // after sample + mu

    gs_fill<<<2048, 256, 0, stream>>>(std_base);
    gs_gemm<<<NROWS, 256, 0, stream>>>(x, W, b, eps, out);
}

// Round 5
// 317.617 us; speedup vs baseline: 1.1760x; 1.1760x over previous
//
#include <hip/hip_runtime.h>
#include <math.h>

#define NDIM 512
#define NROWS 256  // B*S = 2*128

typedef float vfloat4 __attribute__((ext_vector_type(4)));

// ---------------------------------------------------------------------------
// Fused zero-fill + GEMM + softplus + sample + diagonal scatter.
// One block per row (256 blocks x 1024 threads):
//   1. zero-fill the row's own 1 MiB slice of std_mat (coalesced dwordx4,
//      64 iters x 1024 threads x 16 B)
//   2. __syncthreads (drains vmcnt -> fill complete, xs staged)
//   3. thread t computes stats column t: dot(x_row, W_row_t) + b[t]
//      (t<512 -> softplus/var half, t>=512 -> mu half); x row broadcast
//      from LDS, W rows stream through L1 with full line reuse
//   4. var/mu exchanged via LDS; threads 0..511 write sample, mu, and the
//      diagonal element (safe: same block filled those bytes before the
//      barrier)
// This is also the discriminating experiment for the 4x HBM write
// amplification seen on every d_out write so far: this kernel's WRITE_SIZE
// row will show ~263e3 KB (no amplification) or ~1.05e6 KB (intrinsic 4x).
// ---------------------------------------------------------------------------
__global__ __launch_bounds__(1024) void gs_fused(const float* __restrict__ x,
                                                 const float* __restrict__ W,
                                                 const float* __restrict__ b,
                                                 const float* __restrict__ eps,
                                                 float* __restrict__ out) {
    __shared__ float xs[NDIM];
    __shared__ float vs[NDIM];
    __shared__ float ms[NDIM];

    const int r   = blockIdx.x;
    const int tid = threadIdx.x;

    float* out_sample = out;
    float* out_mu     = out + (size_t)NROWS * NDIM;
    float* out_std    = out + (size_t)2 * NROWS * NDIM;
    float* std_row    = out_std + (size_t)r * NDIM * NDIM;  // this block's 1 MiB

    // Stage x row into LDS (first 512 threads).
    if (tid < NDIM) xs[tid] = x[(size_t)r * NDIM + tid];

    // Zero-fill this row's 512x512 fp32 slice: 65536 x 16B, 1024 threads.
    {
        vfloat4* p = (vfloat4*)std_row;
        const vfloat4 z = {0.f, 0.f, 0.f, 0.f};
        #pragma unroll 8
        for (int it = 0; it < 64; ++it)
            p[(size_t)it * 1024 + tid] = z;
    }

    __syncthreads();  // xs visible; fill stores drained (vmcnt(0) before barrier)

    // Thread t: dot(x_row, W[t,:]) + b[t]. Lanes read distinct W rows; each
    // 64B line fetched serves 4 consecutive float4 iters via L1.
    const float4* wr  = (const float4*)(W + (size_t)tid * NDIM);
    const float4* xs4 = (const float4*)xs;
    float s = 0.f;
    #pragma unroll 8
    for (int k = 0; k < NDIM / 4; ++k) {
        float4 wv = wr[k];
        float4 xv = xs4[k];  // wave-uniform -> LDS broadcast, conflict-free
        s += xv.x * wv.x + xv.y * wv.y + xv.z * wv.z + xv.w * wv.w;
    }
    s += b[tid];

    if (tid < NDIM)
        vs[tid] = (s > 20.f) ? s : log1pf(expf(s));  // softplus, stable
    else
        ms[tid - NDIM] = s;                          // mu
    __syncthreads();

    if (tid < NDIM) {
        const float var = vs[tid];
        const float mu  = ms[tid];
        const float smp = mu + sqrtf(var) * eps[(size_t)r * NDIM + tid];
        out_sample[(size_t)r * NDIM + tid] = smp;
        out_mu[(size_t)r * NDIM + tid]     = mu;
        std_row[(size_t)tid * NDIM + tid]  = var;  // diagonal (region zeroed above)
    }
}

extern "C" void kernel_launch(void* const* d_in, const int* in_sizes, int n_in,
                              void* d_out, int out_size, void* d_ws, size_t ws_size,
                              hipStream_t stream) {
    const float* x   = (const float*)d_in[0];
    const float* W   = (const float*)d_in[1];
    const float* b   = (const float*)d_in[2];
    const float* eps = (const float*)d_in[3];
    float* out = (float*)d_out;

    gs_fused<<<NROWS, 1024, 0, stream>>>(x, W, b, eps, out);
}